// Round 1
// baseline (1349.053 us; speedup 1.0000x reference)
//
#include <hip/hip_runtime.h>

#define NB   4
#define C_IN 256
#define CQD  64
#define NPT  4096

// ---------------------------------------------------------------------------
// Kernel A: fused pointwise projections q/k/v  (weights [out_c, C] row-major)
// grid (6 o-chunks, N/64, B), block 256.  o-chunk 0=q, 1=k, 2..5=v rows.
// ---------------------------------------------------------------------------
__global__ __launch_bounds__(256) void proj_kernel(
    const float* __restrict__ x,
    const float* __restrict__ wq, const float* __restrict__ bq,
    const float* __restrict__ wk, const float* __restrict__ bk,
    const float* __restrict__ wv, const float* __restrict__ bv,
    float* __restrict__ qws, float* __restrict__ kws, float* __restrict__ vws)
{
    __shared__ float in_t[64][64];   // [c][n]
    __shared__ float w_t[64][68];    // [c][o], padded

    const int t     = threadIdx.x;
    const int chunk = blockIdx.x;
    const int n0    = blockIdx.y * 64;
    const int b     = blockIdx.z;

    const float* wsrc; const float* bsrc; float* dst; int orow0; int oc;
    if (chunk == 0)      { wsrc = wq; bsrc = bq; dst = qws; orow0 = 0;            oc = CQD;  }
    else if (chunk == 1) { wsrc = wk; bsrc = bk; dst = kws; orow0 = 0;            oc = CQD;  }
    else                 { wsrc = wv; bsrc = bv; dst = vws; orow0 = (chunk-2)*64; oc = C_IN; }

    const int jj = t & 63;
    const int i0 = t >> 6;   // 0..3
    const int to = t >> 4;   // 0..15 -> o rows 4*to..
    const int tn = t & 15;   // 0..15 -> n cols 4*tn..

    float acc[4][4];
    #pragma unroll
    for (int i = 0; i < 4; i++)
        #pragma unroll
        for (int j = 0; j < 4; j++) acc[i][j] = 0.f;

    for (int c0 = 0; c0 < C_IN; c0 += 64) {
        __syncthreads();
        #pragma unroll
        for (int r = 0; r < 16; r++) {
            const int ci = i0 + 4*r;
            in_t[ci][jj] = x[((size_t)b*C_IN + c0 + ci)*NPT + n0 + jj];
            w_t[jj][ci]  = wsrc[(size_t)(orow0 + ci)*C_IN + c0 + jj];
        }
        __syncthreads();
        #pragma unroll 4
        for (int c = 0; c < 64; c++) {
            const float4 w4 = *(const float4*)&w_t[c][4*to];
            const float4 x4 = *(const float4*)&in_t[c][4*tn];
            const float wr[4] = {w4.x, w4.y, w4.z, w4.w};
            const float xr[4] = {x4.x, x4.y, x4.z, x4.w};
            #pragma unroll
            for (int i = 0; i < 4; i++)
                #pragma unroll
                for (int j = 0; j < 4; j++)
                    acc[i][j] += wr[i] * xr[j];
        }
    }
    #pragma unroll
    for (int i = 0; i < 4; i++) {
        const int row  = orow0 + 4*to + i;
        const float bb = bsrc[row];
        float4 o4;
        o4.x = acc[i][0] + bb; o4.y = acc[i][1] + bb;
        o4.z = acc[i][2] + bb; o4.w = acc[i][3] + bb;
        *(float4*)&dst[((size_t)b*oc + row)*NPT + n0 + 4*tn] = o4;
    }
}

// ---------------------------------------------------------------------------
// Kernel B: per-row softmax stats (max, sum-exp) over a 1024-wide m-split.
// grid (4 m-splits, N/64 row tiles, B), block 256.
// ---------------------------------------------------------------------------
__global__ __launch_bounds__(256) void stats_kernel(
    const float* __restrict__ qws, const float* __restrict__ kws,
    float* __restrict__ pmax, float* __restrict__ psum)
{
    __shared__ float  q_t[64][64];       // [d][n]
    __shared__ float  k_t[64][64];       // [d][m]
    __shared__ float2 red[64][16];

    const int t  = threadIdx.x;
    const int ms = blockIdx.x;
    const int n0 = blockIdx.y * 64;
    const int b  = blockIdx.z;
    const int jj = t & 63;
    const int i0 = t >> 6;
    const int tn = t >> 4;   // row group: rows 4*tn..
    const int tm = t & 15;   // col group: cols 4*tm..

    #pragma unroll
    for (int r = 0; r < 16; r++) {
        const int d = i0 + 4*r;
        q_t[d][jj] = qws[((size_t)b*CQD + d)*NPT + n0 + jj];
    }

    float lmax[4], lsum[4];
    #pragma unroll
    for (int i = 0; i < 4; i++) { lmax[i] = -3.0e38f; lsum[i] = 0.f; }

    for (int mt = 0; mt < 16; mt++) {
        const int m0 = ms*1024 + mt*64;
        __syncthreads();
        #pragma unroll
        for (int r = 0; r < 16; r++) {
            const int d = i0 + 4*r;
            k_t[d][jj] = kws[((size_t)b*CQD + d)*NPT + m0 + jj];
        }
        __syncthreads();
        float s[4][4];
        #pragma unroll
        for (int i = 0; i < 4; i++)
            #pragma unroll
            for (int j = 0; j < 4; j++) s[i][j] = 0.f;
        #pragma unroll 4
        for (int d = 0; d < 64; d++) {
            const float4 q4 = *(const float4*)&q_t[d][4*tn];
            const float4 k4 = *(const float4*)&k_t[d][4*tm];
            const float qr[4] = {q4.x, q4.y, q4.z, q4.w};
            const float kr[4] = {k4.x, k4.y, k4.z, k4.w};
            #pragma unroll
            for (int i = 0; i < 4; i++)
                #pragma unroll
                for (int j = 0; j < 4; j++)
                    s[i][j] += qr[i] * kr[j];
        }
        #pragma unroll
        for (int i = 0; i < 4; i++) {
            const float tmax = fmaxf(fmaxf(s[i][0], s[i][1]), fmaxf(s[i][2], s[i][3]));
            const float nm   = fmaxf(lmax[i], tmax);
            const float add  = __expf(s[i][0]-nm) + __expf(s[i][1]-nm)
                             + __expf(s[i][2]-nm) + __expf(s[i][3]-nm);
            lsum[i] = lsum[i]*__expf(lmax[i]-nm) + add;
            lmax[i] = nm;
        }
    }
    #pragma unroll
    for (int i = 0; i < 4; i++) red[4*tn+i][tm] = make_float2(lmax[i], lsum[i]);
    __syncthreads();
    if (t < 64) {
        float M = -3.0e38f, Z = 0.f;
        #pragma unroll 4
        for (int u = 0; u < 16; u++) {
            const float2 pz = red[t][u];
            const float nm  = fmaxf(M, pz.x);
            Z = Z*__expf(M-nm) + pz.y*__expf(pz.x-nm);
            M = nm;
        }
        const size_t idx = ((size_t)(b*4 + ms))*NPT + n0 + t;
        pmax[idx] = M; psum[idx] = Z;
    }
}

// ---------------------------------------------------------------------------
// Merge the 4 m-split partial stats into M[n], 1/Z[n].
// ---------------------------------------------------------------------------
__global__ void merge_kernel(const float* __restrict__ pmax, const float* __restrict__ psum,
                             float* __restrict__ Mrow, float* __restrict__ iZrow)
{
    const int g = blockIdx.x*256 + threadIdx.x;   // 0..16383
    const int b = g >> 12;
    const int n = g & 4095;
    float M = -3.0e38f, Z = 0.f;
    #pragma unroll
    for (int s = 0; s < 4; s++) {
        const float m  = pmax[((size_t)(b*4+s))*NPT + n];
        const float z  = psum[((size_t)(b*4+s))*NPT + n];
        const float nm = fmaxf(M, m);
        Z = Z*__expf(M-nm) + z*__expf(m-nm);
        M = nm;
    }
    Mrow[(size_t)b*NPT + n]  = M;
    iZrow[(size_t)b*NPT + n] = 1.f/Z;
}

// ---------------------------------------------------------------------------
// out = inputs (residual pre-fill; attn kernel atomically adds gamma*o)
// ---------------------------------------------------------------------------
__global__ void init_out_kernel(const float* __restrict__ x, float* __restrict__ out)
{
    const size_t i = ((size_t)blockIdx.x*256 + threadIdx.x)*4;
    *(float4*)&out[i] = *(const float4*)&x[i];
}

// ---------------------------------------------------------------------------
// Kernel C: recompute s-tiles, p = exp(s-M)/Z, accumulate o += v@p.
// grid (4 n-splits, N/64 m-tiles, B), block 256. atomicAdd gamma*o into out.
// ---------------------------------------------------------------------------
__global__ __launch_bounds__(256) void attn_out_kernel(
    const float* __restrict__ qws, const float* __restrict__ kws, const float* __restrict__ vws,
    const float* __restrict__ Mrow, const float* __restrict__ iZrow,
    const float* __restrict__ gamma, float* __restrict__ out)
{
    __shared__ float k_t[64][64];            // [d][m]   16 KB
    __shared__ float q_t[64][32];            // [d][n]    8 KB
    __shared__ float p_t[32][64];            // [n][m]    8 KB
    __shared__ unsigned short v_t[32][260];  // [n][c] bf16, padded  16.25 KB
    __shared__ float Ml[32];
    __shared__ float iZl[32];

    const int t   = threadIdx.x;
    const int nsp = blockIdx.x;
    const int m0  = blockIdx.y * 64;
    const int b   = blockIdx.z;

    const int jj = t & 63;
    const int i0 = t >> 6;
    #pragma unroll
    for (int r = 0; r < 16; r++) {
        const int d = i0 + 4*r;
        k_t[d][jj] = kws[((size_t)b*CQD + d)*NPT + m0 + jj];
    }

    const int tm = t & 15;   // m col group: cols 4*tm..   (both stages)
    const int tg = t >> 4;   // s-stage: rows 2*tg..; o-stage: c = 16*tg..
    const int j2 = t & 31;
    const int c8 = t >> 5;

    float acc[16][4];
    #pragma unroll
    for (int i = 0; i < 16; i++)
        #pragma unroll
        for (int j = 0; j < 4; j++) acc[i][j] = 0.f;

    for (int nt = 0; nt < 32; nt++) {
        const int n0 = nsp*1024 + nt*32;
        __syncthreads();
        #pragma unroll
        for (int r = 0; r < 8; r++) {
            const int d = c8 + 8*r;
            q_t[d][j2] = qws[((size_t)b*CQD + d)*NPT + n0 + j2];
        }
        #pragma unroll
        for (int r = 0; r < 32; r++) {
            const int c  = c8 + 8*r;
            const float vv = vws[((size_t)b*C_IN + c)*NPT + n0 + j2];
            v_t[j2][c] = (unsigned short)(__float_as_uint(vv) >> 16);
        }
        if (t < 32) {
            Ml[t]  = Mrow[(size_t)b*NPT + n0 + t];
            iZl[t] = iZrow[(size_t)b*NPT + n0 + t];
        }
        __syncthreads();

        // ---- s tile: rows 2*tg..2*tg+1, cols 4*tm..4*tm+3 ----
        float s[2][4];
        #pragma unroll
        for (int i = 0; i < 2; i++)
            #pragma unroll
            for (int j = 0; j < 4; j++) s[i][j] = 0.f;
        #pragma unroll 8
        for (int d = 0; d < 64; d++) {
            const float2 q2 = *(const float2*)&q_t[d][2*tg];
            const float4 k4 = *(const float4*)&k_t[d][4*tm];
            const float qr[2] = {q2.x, q2.y};
            const float kr[4] = {k4.x, k4.y, k4.z, k4.w};
            #pragma unroll
            for (int i = 0; i < 2; i++)
                #pragma unroll
                for (int j = 0; j < 4; j++)
                    s[i][j] += qr[i] * kr[j];
        }
        #pragma unroll
        for (int i = 0; i < 2; i++) {
            const int row = 2*tg + i;
            const float m = Ml[row], z = iZl[row];
            float4 p4;
            p4.x = __expf(s[i][0]-m)*z;
            p4.y = __expf(s[i][1]-m)*z;
            p4.z = __expf(s[i][2]-m)*z;
            p4.w = __expf(s[i][3]-m)*z;
            *(float4*)&p_t[row][4*tm] = p4;
        }
        __syncthreads();

        // ---- o tile: acc[c=16*tg+i][m=4*tm+j] += v[c,n] * p[n,m] ----
        #pragma unroll 2
        for (int n = 0; n < 32; n++) {
            const float4 p4 = *(const float4*)&p_t[n][4*tm];
            const float pr[4] = {p4.x, p4.y, p4.z, p4.w};
            const unsigned int* vp = (const unsigned int*)&v_t[n][16*tg];
            #pragma unroll
            for (int u = 0; u < 8; u++) {
                const unsigned int w = vp[u];
                const float vlo = __uint_as_float(w << 16);
                const float vhi = __uint_as_float(w & 0xffff0000u);
                #pragma unroll
                for (int j = 0; j < 4; j++) {
                    acc[2*u][j]   += vlo * pr[j];
                    acc[2*u+1][j] += vhi * pr[j];
                }
            }
        }
    }

    const float g = gamma[0];
    #pragma unroll
    for (int i = 0; i < 16; i++) {
        #pragma unroll
        for (int j = 0; j < 4; j++) {
            atomicAdd(&out[((size_t)b*C_IN + 16*tg + i)*NPT + m0 + 4*tm + j], g*acc[i][j]);
        }
    }
}

// ---------------------------------------------------------------------------
extern "C" void kernel_launch(void* const* d_in, const int* in_sizes, int n_in,
                              void* d_out, int out_size, void* d_ws, size_t ws_size,
                              hipStream_t stream)
{
    const float* x     = (const float*)d_in[0];
    const float* wq    = (const float*)d_in[1];
    const float* bq    = (const float*)d_in[2];
    const float* wk    = (const float*)d_in[3];
    const float* bk    = (const float*)d_in[4];
    const float* wv    = (const float*)d_in[5];
    const float* bv    = (const float*)d_in[6];
    const float* gamma = (const float*)d_in[7];
    float* out = (float*)d_out;

    float* ws    = (float*)d_ws;
    float* qws   = ws;                                 // 4*64*4096
    float* kws   = qws  + (size_t)NB*CQD*NPT;          // 4*64*4096
    float* vws   = kws  + (size_t)NB*CQD*NPT;          // 4*256*4096
    float* pmax  = vws  + (size_t)NB*C_IN*NPT;         // 4*4*4096
    float* psum  = pmax + (size_t)NB*4*NPT;            // 4*4*4096
    float* Mrow  = psum + (size_t)NB*4*NPT;            // 4*4096
    float* iZrow = Mrow + (size_t)NB*NPT;              // 4*4096
    // total ~25.8 MB of workspace

    proj_kernel<<<dim3(6, NPT/64, NB), 256, 0, stream>>>(x, wq, bq, wk, bk, wv, bv,
                                                         qws, kws, vws);
    stats_kernel<<<dim3(4, NPT/64, NB), 256, 0, stream>>>(qws, kws, pmax, psum);
    merge_kernel<<<dim3(64), 256, 0, stream>>>(pmax, psum, Mrow, iZrow);
    init_out_kernel<<<dim3(4096), 256, 0, stream>>>(x, out);
    attn_out_kernel<<<dim3(4, NPT/64, NB), 256, 0, stream>>>(qws, kws, vws,
                                                             Mrow, iZrow, gamma, out);
}

// Round 2
// 414.940 us; speedup vs baseline: 3.2512x; 3.2512x over previous
//
#include <hip/hip_runtime.h>

#define NB   4
#define C_IN 256
#define CQD  64
#define NPT  4096
#define L2E  1.44269504088896f

typedef __attribute__((ext_vector_type(8))) short bf16x8;
typedef __attribute__((ext_vector_type(4))) float f32x4;
typedef unsigned short u16;
typedef unsigned int   u32;

__device__ __forceinline__ u16 f2bf(float f) {
    u32 u = __float_as_uint(f);
    u += 0x7fff + ((u >> 16) & 1);   // round-to-nearest-even
    return (u16)(u >> 16);
}

// ---------------------------------------------------------------------------
// Kernel A: fused pointwise projections q/k/v  (fp32 compute, bf16 outputs)
// qT/kT layout: [b][n][64] (transposed, MFMA-fragment friendly)
// vbf layout:   [b][c][n]
// grid (6 o-chunks, N/64, B), block 256. chunk 0=q, 1=k, 2..5=v rows.
// ---------------------------------------------------------------------------
__global__ __launch_bounds__(256) void proj_kernel(
    const float* __restrict__ x,
    const float* __restrict__ wq, const float* __restrict__ bq,
    const float* __restrict__ wk, const float* __restrict__ bk,
    const float* __restrict__ wv, const float* __restrict__ bv,
    u16* __restrict__ qT, u16* __restrict__ kT, u16* __restrict__ vbf)
{
    __shared__ float in_t[64][64];   // [c][n]
    __shared__ float w_t[64][68];    // [c][o], padded
    __shared__ float t_l[64][65];    // transpose staging [n][o]

    const int t     = threadIdx.x;
    const int chunk = blockIdx.x;
    const int n0    = blockIdx.y * 64;
    const int b     = blockIdx.z;

    const float* wsrc; const float* bsrc; int orow0;
    if (chunk == 0)      { wsrc = wq; bsrc = bq; orow0 = 0; }
    else if (chunk == 1) { wsrc = wk; bsrc = bk; orow0 = 0; }
    else                 { wsrc = wv; bsrc = bv; orow0 = (chunk-2)*64; }

    const int jj = t & 63;
    const int i0 = t >> 6;   // 0..3
    const int to = t >> 4;   // 0..15 -> o rows 4*to..
    const int tn = t & 15;   // 0..15 -> n cols 4*tn..

    float acc[4][4];
    #pragma unroll
    for (int i = 0; i < 4; i++)
        #pragma unroll
        for (int j = 0; j < 4; j++) acc[i][j] = 0.f;

    for (int c0 = 0; c0 < C_IN; c0 += 64) {
        __syncthreads();
        #pragma unroll
        for (int r = 0; r < 16; r++) {
            const int ci = i0 + 4*r;
            in_t[ci][jj] = x[((size_t)b*C_IN + c0 + ci)*NPT + n0 + jj];
            w_t[jj][ci]  = wsrc[(size_t)(orow0 + ci)*C_IN + c0 + jj];
        }
        __syncthreads();
        #pragma unroll 4
        for (int c = 0; c < 64; c++) {
            const float4 w4 = *(const float4*)&w_t[c][4*to];
            const float4 x4 = *(const float4*)&in_t[c][4*tn];
            const float wr[4] = {w4.x, w4.y, w4.z, w4.w};
            const float xr[4] = {x4.x, x4.y, x4.z, x4.w};
            #pragma unroll
            for (int i = 0; i < 4; i++)
                #pragma unroll
                for (int j = 0; j < 4; j++)
                    acc[i][j] += wr[i] * xr[j];
        }
    }

    if (chunk < 2) {
        u16* dst = (chunk == 0) ? qT : kT;
        // stage transposed [n][o] with bias
        #pragma unroll
        for (int i = 0; i < 4; i++) {
            const float bb = bsrc[4*to + i];
            #pragma unroll
            for (int j = 0; j < 4; j++)
                t_l[4*tn + j][4*to + i] = acc[i][j] + bb;
        }
        __syncthreads();
        #pragma unroll
        for (int it = 0; it < 2; it++) {
            const int idx = t + 256*it;
            const int n = idx >> 3, ch = idx & 7;
            u32 pk[4];
            #pragma unroll
            for (int e = 0; e < 4; e++) {
                pk[e] = (u32)f2bf(t_l[n][8*ch + 2*e])
                      | ((u32)f2bf(t_l[n][8*ch + 2*e + 1]) << 16);
            }
            *(uint4*)&dst[((size_t)b*NPT + n0 + n)*CQD + 8*ch] =
                make_uint4(pk[0], pk[1], pk[2], pk[3]);
        }
    } else {
        #pragma unroll
        for (int i = 0; i < 4; i++) {
            const int row = orow0 + 4*to + i;
            const float bb = bsrc[row];
            ushort4 o4;
            o4.x = f2bf(acc[i][0] + bb);
            o4.y = f2bf(acc[i][1] + bb);
            o4.z = f2bf(acc[i][2] + bb);
            o4.w = f2bf(acc[i][3] + bb);
            *(ushort4*)&vbf[((size_t)b*C_IN + row)*NPT + n0 + 4*tn] = o4;
        }
    }
}

// ---------------------------------------------------------------------------
// Kernel B: per-row softmax stats via bf16 MFMA. One block per 64 n-rows.
// Emits Lrow[n] = M[n]*log2e + log2(Z[n]) so pass2 does exp2(s*l2e - Lrow).
// grid (N/64, B), block 256 (4 waves; wave w owns rows 16w..16w+16).
// ---------------------------------------------------------------------------
__global__ __launch_bounds__(256) void stats_kernel(
    const u16* __restrict__ qT, const u16* __restrict__ kT,
    float* __restrict__ Lrow)
{
    const int t = threadIdx.x;
    const int w = t >> 6, l = t & 63, q = l >> 4, c16 = l & 15;
    const int nt = blockIdx.x, b = blockIdx.y;
    const int nb = nt*64 + 16*w;

    const bf16x8* qp = (const bf16x8*)&qT[((size_t)b*NPT + nb + c16)*CQD + 8*q];
    const bf16x8 aq0 = qp[0];
    const bf16x8 aq1 = qp[4];   // +32 elements

    float rm[4], rz[4];
    #pragma unroll
    for (int r = 0; r < 4; r++) { rm[r] = -3.0e38f; rz[r] = 0.f; }

    for (int m0 = 0; m0 < NPT; m0 += 64) {
        f32x4 s[4];
        #pragma unroll
        for (int mj = 0; mj < 4; mj++) {
            const bf16x8* kp = (const bf16x8*)&kT[((size_t)b*NPT + m0 + 16*mj + c16)*CQD + 8*q];
            f32x4 a = {0.f, 0.f, 0.f, 0.f};
            a = __builtin_amdgcn_mfma_f32_16x16x32_bf16(aq0, kp[0], a, 0, 0, 0);
            a = __builtin_amdgcn_mfma_f32_16x16x32_bf16(aq1, kp[4], a, 0, 0, 0);
            s[mj] = a;
        }
        #pragma unroll
        for (int r = 0; r < 4; r++) {
            const float v0 = s[0][r], v1 = s[1][r], v2 = s[2][r], v3 = s[3][r];
            const float mx = fmaxf(fmaxf(v0, v1), fmaxf(v2, v3));
            const float nm = fmaxf(rm[r], mx);
            const float za = exp2f((v0-nm)*L2E) + exp2f((v1-nm)*L2E)
                           + exp2f((v2-nm)*L2E) + exp2f((v3-nm)*L2E);
            rz[r] = rz[r]*exp2f((rm[r]-nm)*L2E) + za;
            rm[r] = nm;
        }
    }
    #pragma unroll
    for (int r = 0; r < 4; r++) {
        float M = rm[r], Z = rz[r];
        #pragma unroll
        for (int d = 1; d < 16; d <<= 1) {
            const float Mo = __shfl_xor(M, d, 64);
            const float Zo = __shfl_xor(Z, d, 64);
            const float nm = fmaxf(M, Mo);
            Z = Z*exp2f((M-nm)*L2E) + Zo*exp2f((Mo-nm)*L2E);
            M = nm;
        }
        if (c16 == 0)
            Lrow[(size_t)b*NPT + nb + 4*q + r] = M*L2E + log2f(Z);
    }
}

// ---------------------------------------------------------------------------
// Kernel C: pass 2. Per block: one 64-wide m-tile, all 256 c.
// s recompute (MFMA) -> p = exp2(s*l2e - Lrow) -> LDS -> PV (MFMA).
// Epilogue fuses residual: out = gamma*o + x.
// grid (N/64, B), block 256.
// ---------------------------------------------------------------------------
__global__ __launch_bounds__(256) void attn_kernel(
    const u16* __restrict__ qT, const u16* __restrict__ kT, const u16* __restrict__ vbf,
    const float* __restrict__ Lrow, const float* __restrict__ gamma,
    const float* __restrict__ x, float* __restrict__ out)
{
    __shared__ u16  p_l[64][72];   // [m][n'] bf16, stride 144B (16B-aligned b128)
    __shared__ float Ll[64];

    const int t = threadIdx.x;
    const int w = t >> 6, l = t & 63, q = l >> 4, c16 = l & 15;
    const int mt = blockIdx.x, b = blockIdx.y;
    const int m0 = mt * 64;

    // k B-fragments: constant over the whole n loop -> registers (32 VGPRs)
    bf16x8 kf[4][2];
    #pragma unroll
    for (int mj = 0; mj < 4; mj++) {
        const bf16x8* kp = (const bf16x8*)&kT[((size_t)b*NPT + m0 + 16*mj + c16)*CQD + 8*q];
        kf[mj][0] = kp[0];
        kf[mj][1] = kp[4];
    }

    f32x4 acc[4][4];   // [ci][mj]: c = 64w+16ci+4q+r, m = m0+16mj+c16
    #pragma unroll
    for (int ci = 0; ci < 4; ci++)
        #pragma unroll
        for (int mj = 0; mj < 4; mj++)
            acc[ci][mj] = (f32x4){0.f, 0.f, 0.f, 0.f};

    for (int nt = 0; nt < 64; nt++) {
        const int n0 = nt * 64;
        if (t < 64) Ll[t] = Lrow[(size_t)b*NPT + n0 + t];
        const bf16x8* qp = (const bf16x8*)&qT[((size_t)b*NPT + n0 + 16*w + c16)*CQD + 8*q];
        const bf16x8 qa0 = qp[0];
        const bf16x8 qa1 = qp[4];
        __syncthreads();

        // s tiles: wave w computes n' rows 16w..16w+16, all 64 m
        f32x4 s[4];
        #pragma unroll
        for (int mj = 0; mj < 4; mj++) {
            f32x4 a = {0.f, 0.f, 0.f, 0.f};
            a = __builtin_amdgcn_mfma_f32_16x16x32_bf16(qa0, kf[mj][0], a, 0, 0, 0);
            a = __builtin_amdgcn_mfma_f32_16x16x32_bf16(qa1, kf[mj][1], a, 0, 0, 0);
            s[mj] = a;
        }
        float Lr[4];
        #pragma unroll
        for (int r = 0; r < 4; r++) Lr[r] = Ll[16*w + 4*q + r];
        #pragma unroll
        for (int mj = 0; mj < 4; mj++) {
            const u32 lo = (u32)f2bf(exp2f(s[mj][0]*L2E - Lr[0]))
                         | ((u32)f2bf(exp2f(s[mj][1]*L2E - Lr[1])) << 16);
            const u32 hi = (u32)f2bf(exp2f(s[mj][2]*L2E - Lr[2]))
                         | ((u32)f2bf(exp2f(s[mj][3]*L2E - Lr[3])) << 16);
            *(uint2*)&p_l[16*mj + c16][16*w + 4*q] = make_uint2(lo, hi);
        }
        __syncthreads();

        // PV: o[c, m] += v[c, n'] @ p[n', m]
        #pragma unroll
        for (int ci = 0; ci < 4; ci++) {
            const int c = 64*w + 16*ci + c16;
            const bf16x8* vp = (const bf16x8*)&vbf[((size_t)b*C_IN + c)*NPT + n0 + 8*q];
            const bf16x8 va0 = vp[0];
            const bf16x8 va1 = vp[4];
            #pragma unroll
            for (int mj = 0; mj < 4; mj++) {
                const bf16x8* pp = (const bf16x8*)&p_l[16*mj + c16][8*q];
                acc[ci][mj] = __builtin_amdgcn_mfma_f32_16x16x32_bf16(va0, pp[0], acc[ci][mj], 0, 0, 0);
                acc[ci][mj] = __builtin_amdgcn_mfma_f32_16x16x32_bf16(va1, pp[4], acc[ci][mj], 0, 0, 0);
            }
        }
    }

    const float g = gamma[0];
    #pragma unroll
    for (int ci = 0; ci < 4; ci++)
        #pragma unroll
        for (int mj = 0; mj < 4; mj++)
            #pragma unroll
            for (int r = 0; r < 4; r++) {
                const size_t o = ((size_t)b*C_IN + 64*w + 16*ci + 4*q + r)*NPT
                               + m0 + 16*mj + c16;
                out[o] = g*acc[ci][mj][r] + x[o];
            }
}

// ---------------------------------------------------------------------------
extern "C" void kernel_launch(void* const* d_in, const int* in_sizes, int n_in,
                              void* d_out, int out_size, void* d_ws, size_t ws_size,
                              hipStream_t stream)
{
    const float* x     = (const float*)d_in[0];
    const float* wq    = (const float*)d_in[1];
    const float* bq    = (const float*)d_in[2];
    const float* wk    = (const float*)d_in[3];
    const float* bk    = (const float*)d_in[4];
    const float* wv    = (const float*)d_in[5];
    const float* bv    = (const float*)d_in[6];
    const float* gamma = (const float*)d_in[7];
    float* out = (float*)d_out;

    u16* qT  = (u16*)d_ws;                           // 4*4096*64  bf16 = 2 MB
    u16* kT  = qT  + (size_t)NB*NPT*CQD;             // 2 MB
    u16* vbf = kT  + (size_t)NB*NPT*CQD;             // 4*256*4096 bf16 = 8 MB
    float* Lrow = (float*)(vbf + (size_t)NB*C_IN*NPT);  // 64 KB

    proj_kernel<<<dim3(6, NPT/64, NB), 256, 0, stream>>>(x, wq, bq, wk, bk, wv, bv,
                                                         qT, kT, vbf);
    stats_kernel<<<dim3(NPT/64, NB), 256, 0, stream>>>(qT, kT, Lrow);
    attn_kernel<<<dim3(NPT/64, NB), 256, 0, stream>>>(qT, kT, vbf, Lrow, gamma, x, out);
}

// Round 3
// 288.344 us; speedup vs baseline: 4.6786x; 1.4390x over previous
//
#include <hip/hip_runtime.h>

#define NB   4
#define C_IN 256
#define CQD  64
#define NPT  4096
#define L2E  1.44269504088896f

typedef __attribute__((ext_vector_type(8))) short bf16x8;
typedef __attribute__((ext_vector_type(4))) float f32x4;
typedef unsigned short u16;
typedef unsigned int   u32;

__device__ __forceinline__ u16 f2bf(float f) {
    u32 u = __float_as_uint(f);
    u += 0x7fff + ((u >> 16) & 1);   // round-to-nearest-even
    return (u16)(u >> 16);
}

// ---------------------------------------------------------------------------
// prep: pack wq|wk|wv into bf16 wbf[384][256], biases into bias[384]
// ---------------------------------------------------------------------------
__global__ void prep_kernel(
    const float* __restrict__ wq, const float* __restrict__ bq,
    const float* __restrict__ wk, const float* __restrict__ bk,
    const float* __restrict__ wv, const float* __restrict__ bv,
    u16* __restrict__ wbf, float* __restrict__ bias)
{
    const int gid = blockIdx.x*256 + threadIdx.x;
    if (gid < 384*256) {
        const int r = gid >> 8, c = gid & 255;
        const float v = (r < 64) ? wq[r*256 + c]
                      : (r < 128) ? wk[(r-64)*256 + c]
                                  : wv[(r-128)*256 + c];
        wbf[gid] = f2bf(v);
    } else if (gid < 384*256 + 384) {
        const int r = gid - 384*256;
        bias[r] = (r < 64) ? bq[r] : (r < 128) ? bk[r-64] : bv[r-128];
    }
}

// ---------------------------------------------------------------------------
// proj: MFMA pointwise projections, x read ONCE.
// out rows 0..63 -> qT[b][n][64], 64..127 -> kT[b][n][64], 128..383 -> vbf[b][c][n]
// grid (N/32, B), block 256 (4 waves; wave w owns output rows 96w..96w+95).
// ---------------------------------------------------------------------------
__global__ __launch_bounds__(256) void proj_kernel(
    const float* __restrict__ x, const u16* __restrict__ wbf,
    const float* __restrict__ bias,
    u16* __restrict__ qT, u16* __restrict__ kT, u16* __restrict__ vbf)
{
    __shared__ __align__(16) u16 x_t[32][264];   // [n][c] bf16, stride 528B

    const int t  = threadIdx.x;
    const int n0 = blockIdx.x * 32;
    const int b  = blockIdx.y;

    // stage x tile transposed -> bf16 LDS (once per block)
    {
        const int ln = t & 31;       // n lane
        const int cg = t >> 5;       // 0..7
        #pragma unroll
        for (int rr = 0; rr < 8; rr++) {
            const int c = 4*cg + 32*rr;
            const float f0 = x[((size_t)(b*C_IN + c+0))*NPT + n0 + ln];
            const float f1 = x[((size_t)(b*C_IN + c+1))*NPT + n0 + ln];
            const float f2 = x[((size_t)(b*C_IN + c+2))*NPT + n0 + ln];
            const float f3 = x[((size_t)(b*C_IN + c+3))*NPT + n0 + ln];
            ushort4 u4;
            u4.x = f2bf(f0); u4.y = f2bf(f1); u4.z = f2bf(f2); u4.w = f2bf(f3);
            *(ushort4*)&x_t[ln][c] = u4;
        }
    }
    __syncthreads();

    const int w = t >> 6, l = t & 63, q = l >> 4, c16 = l & 15;

    f32x4 acc[6][2];
    #pragma unroll
    for (int ot = 0; ot < 6; ot++)
        #pragma unroll
        for (int nt = 0; nt < 2; nt++)
            acc[ot][nt] = (f32x4){0.f, 0.f, 0.f, 0.f};

    #pragma unroll
    for (int kk = 0; kk < 8; kk++) {
        const bf16x8 bf0 = *(const bf16x8*)&x_t[c16     ][kk*32 + 8*q];
        const bf16x8 bf1 = *(const bf16x8*)&x_t[16 + c16][kk*32 + 8*q];
        #pragma unroll
        for (int ot = 0; ot < 6; ot++) {
            const int o = 96*w + 16*ot + c16;
            const bf16x8 af = *(const bf16x8*)&wbf[(size_t)o*C_IN + kk*32 + 8*q];
            acc[ot][0] = __builtin_amdgcn_mfma_f32_16x16x32_bf16(af, bf0, acc[ot][0], 0, 0, 0);
            acc[ot][1] = __builtin_amdgcn_mfma_f32_16x16x32_bf16(af, bf1, acc[ot][1], 0, 0, 0);
        }
    }

    // epilogue: D row = 4q+r -> o, col = c16 -> n
    #pragma unroll
    for (int ot = 0; ot < 6; ot++) {
        const int ob = 96*w + 16*ot + 4*q;
        #pragma unroll
        for (int nt = 0; nt < 2; nt++) {
            const int n = n0 + 16*nt + c16;
            float vals[4];
            #pragma unroll
            for (int r = 0; r < 4; r++) vals[r] = acc[ot][nt][r] + bias[ob + r];
            if (ob < 128) {
                ushort4 s4;
                s4.x = f2bf(vals[0]); s4.y = f2bf(vals[1]);
                s4.z = f2bf(vals[2]); s4.w = f2bf(vals[3]);
                if (ob < 64)
                    *(ushort4*)&qT[((size_t)b*NPT + n)*CQD + ob] = s4;
                else
                    *(ushort4*)&kT[((size_t)b*NPT + n)*CQD + (ob - 64)] = s4;
            } else {
                #pragma unroll
                for (int r = 0; r < 4; r++)
                    vbf[((size_t)b*C_IN + ob - 128 + r)*NPT + n] = f2bf(vals[r]);
            }
        }
    }
}

// ---------------------------------------------------------------------------
// stats: partial softmax stats over 1024-wide m-split via MFMA.
// grid (4 msplit, N/64, B), block 256.
// ---------------------------------------------------------------------------
__global__ __launch_bounds__(256) void stats_kernel(
    const u16* __restrict__ qT, const u16* __restrict__ kT,
    float* __restrict__ pmax, float* __restrict__ psum)
{
    const int t = threadIdx.x;
    const int w = t >> 6, l = t & 63, q = l >> 4, c16 = l & 15;
    const int ms = blockIdx.x, nt = blockIdx.y, b = blockIdx.z;
    const int nb = nt*64 + 16*w;

    const bf16x8* qp = (const bf16x8*)&qT[((size_t)b*NPT + nb + c16)*CQD + 8*q];
    const bf16x8 aq0 = qp[0];
    const bf16x8 aq1 = qp[4];

    float rm[4], rz[4];
    #pragma unroll
    for (int r = 0; r < 4; r++) { rm[r] = -3.0e38f; rz[r] = 0.f; }

    for (int m0 = ms*1024; m0 < ms*1024 + 1024; m0 += 64) {
        f32x4 s[4];
        #pragma unroll
        for (int mj = 0; mj < 4; mj++) {
            const bf16x8* kp = (const bf16x8*)&kT[((size_t)b*NPT + m0 + 16*mj + c16)*CQD + 8*q];
            f32x4 a = {0.f, 0.f, 0.f, 0.f};
            a = __builtin_amdgcn_mfma_f32_16x16x32_bf16(aq0, kp[0], a, 0, 0, 0);
            a = __builtin_amdgcn_mfma_f32_16x16x32_bf16(aq1, kp[4], a, 0, 0, 0);
            s[mj] = a;
        }
        #pragma unroll
        for (int r = 0; r < 4; r++) {
            const float v0 = s[0][r], v1 = s[1][r], v2 = s[2][r], v3 = s[3][r];
            const float mx = fmaxf(fmaxf(v0, v1), fmaxf(v2, v3));
            const float nm = fmaxf(rm[r], mx);
            const float za = exp2f((v0-nm)*L2E) + exp2f((v1-nm)*L2E)
                           + exp2f((v2-nm)*L2E) + exp2f((v3-nm)*L2E);
            rz[r] = rz[r]*exp2f((rm[r]-nm)*L2E) + za;
            rm[r] = nm;
        }
    }
    #pragma unroll
    for (int r = 0; r < 4; r++) {
        float M = rm[r], Z = rz[r];
        #pragma unroll
        for (int d = 1; d < 16; d <<= 1) {
            const float Mo = __shfl_xor(M, d, 64);
            const float Zo = __shfl_xor(Z, d, 64);
            const float nm = fmaxf(M, Mo);
            Z = Z*exp2f((M-nm)*L2E) + Zo*exp2f((Mo-nm)*L2E);
            M = nm;
        }
        if (c16 == 0) {
            const size_t idx = ((size_t)(b*4 + ms))*NPT + nb + 4*q + r;
            pmax[idx] = M; psum[idx] = Z;
        }
    }
}

// ---------------------------------------------------------------------------
// merge partial stats -> Lrow[n] = M*log2e + log2(Z)
// ---------------------------------------------------------------------------
__global__ void merge_kernel(const float* __restrict__ pmax, const float* __restrict__ psum,
                             float* __restrict__ Lrow)
{
    const int g = blockIdx.x*256 + threadIdx.x;   // 0..16383
    const int b = g >> 12;
    const int n = g & 4095;
    float M = -3.0e38f, Z = 0.f;
    #pragma unroll
    for (int s = 0; s < 4; s++) {
        const float m  = pmax[((size_t)(b*4+s))*NPT + n];
        const float z  = psum[((size_t)(b*4+s))*NPT + n];
        const float nm = fmaxf(M, m);
        Z = Z*exp2f((M-nm)*L2E) + z*exp2f((m-nm)*L2E);
        M = nm;
    }
    Lrow[(size_t)b*NPT + n] = M*L2E + log2f(Z);
}

// ---------------------------------------------------------------------------
// attn: c-split x4. Block = (64 m) x (64 c-chunk), full n sweep.
// Double-buffered p tile -> ONE barrier per iteration. out = gamma*o + x.
// grid (N/64, 4 csplit, B), block 256.
// ---------------------------------------------------------------------------
__global__ __launch_bounds__(256, 4) void attn_kernel(
    const u16* __restrict__ qT, const u16* __restrict__ kT, const u16* __restrict__ vbf,
    const float* __restrict__ Lrow, const float* __restrict__ gamma,
    const float* __restrict__ x, float* __restrict__ out)
{
    __shared__ __align__(16) u16 p_l[2][64][72];   // double-buffered [m][n'] bf16

    const int t = threadIdx.x;
    const int w = t >> 6, l = t & 63, q = l >> 4, c16 = l & 15;
    const int mt = blockIdx.x, cs = blockIdx.y, b = blockIdx.z;
    const int m0 = mt * 64;

    // k B-fragments: registers for the whole n loop
    bf16x8 kf[4][2];
    #pragma unroll
    for (int mj = 0; mj < 4; mj++) {
        const bf16x8* kp = (const bf16x8*)&kT[((size_t)b*NPT + m0 + 16*mj + c16)*CQD + 8*q];
        kf[mj][0] = kp[0];
        kf[mj][1] = kp[4];
    }

    f32x4 acc[4];   // [mj]: c = cs*64 + 16w + 4q + r, m = m0 + 16mj + c16
    #pragma unroll
    for (int mj = 0; mj < 4; mj++) acc[mj] = (f32x4){0.f, 0.f, 0.f, 0.f};

    const int cA = cs*64 + 16*w + c16;                 // v A-fragment row
    const u16* vbase = &vbf[((size_t)b*C_IN + cA)*NPT];
    const float* Lbase = &Lrow[(size_t)b*NPT + 16*w + 4*q];

    // first q fragment
    const bf16x8* qp0 = (const bf16x8*)&qT[((size_t)b*NPT + 16*w + c16)*CQD + 8*q];
    bf16x8 qa0 = qp0[0];
    bf16x8 qa1 = qp0[4];

    int buf = 0;
    for (int nt = 0; nt < 64; nt++) {
        const int n0 = nt * 64;

        // s tiles: wave w -> n' rows 16w..16w+15, all 64 m
        f32x4 s[4];
        #pragma unroll
        for (int mj = 0; mj < 4; mj++) {
            f32x4 a = {0.f, 0.f, 0.f, 0.f};
            a = __builtin_amdgcn_mfma_f32_16x16x32_bf16(qa0, kf[mj][0], a, 0, 0, 0);
            a = __builtin_amdgcn_mfma_f32_16x16x32_bf16(qa1, kf[mj][1], a, 0, 0, 0);
            s[mj] = a;
        }
        // prefetch next q fragment (hidden behind exp + barrier + PV)
        if (nt < 63) {
            const bf16x8* qp = (const bf16x8*)&qT[((size_t)b*NPT + n0 + 64 + 16*w + c16)*CQD + 8*q];
            qa0 = qp[0];
            qa1 = qp[4];
        }

        float Lr[4];
        #pragma unroll
        for (int r = 0; r < 4; r++) Lr[r] = Lbase[n0 + r];

        #pragma unroll
        for (int mj = 0; mj < 4; mj++) {
            const u32 lo = (u32)f2bf(exp2f(s[mj][0]*L2E - Lr[0]))
                         | ((u32)f2bf(exp2f(s[mj][1]*L2E - Lr[1])) << 16);
            const u32 hi = (u32)f2bf(exp2f(s[mj][2]*L2E - Lr[2]))
                         | ((u32)f2bf(exp2f(s[mj][3]*L2E - Lr[3])) << 16);
            *(uint2*)&p_l[buf][16*mj + c16][16*w + 4*q] = make_uint2(lo, hi);
        }

        // v A-fragments for this n' tile (global, issued before barrier)
        const bf16x8 va0 = *(const bf16x8*)&vbase[n0 + 8*q];
        const bf16x8 va1 = *(const bf16x8*)&vbase[n0 + 32 + 8*q];

        __syncthreads();

        #pragma unroll
        for (int mj = 0; mj < 4; mj++) {
            const bf16x8* pp = (const bf16x8*)&p_l[buf][16*mj + c16][8*q];
            acc[mj] = __builtin_amdgcn_mfma_f32_16x16x32_bf16(va0, pp[0], acc[mj], 0, 0, 0);
            acc[mj] = __builtin_amdgcn_mfma_f32_16x16x32_bf16(va1, pp[4], acc[mj], 0, 0, 0);
        }
        buf ^= 1;
    }

    const float g = gamma[0];
    #pragma unroll
    for (int mj = 0; mj < 4; mj++)
        #pragma unroll
        for (int r = 0; r < 4; r++) {
            const size_t o = ((size_t)b*C_IN + cs*64 + 16*w + 4*q + r)*NPT
                           + m0 + 16*mj + c16;
            out[o] = g*acc[mj][r] + x[o];
        }
}

// ---------------------------------------------------------------------------
extern "C" void kernel_launch(void* const* d_in, const int* in_sizes, int n_in,
                              void* d_out, int out_size, void* d_ws, size_t ws_size,
                              hipStream_t stream)
{
    const float* x     = (const float*)d_in[0];
    const float* wq    = (const float*)d_in[1];
    const float* bq    = (const float*)d_in[2];
    const float* wk    = (const float*)d_in[3];
    const float* bk    = (const float*)d_in[4];
    const float* wv    = (const float*)d_in[5];
    const float* bv    = (const float*)d_in[6];
    const float* gamma = (const float*)d_in[7];
    float* out = (float*)d_out;

    u16* qT  = (u16*)d_ws;                              // 2 MB
    u16* kT  = qT  + (size_t)NB*NPT*CQD;                // 2 MB
    u16* vbf = kT  + (size_t)NB*NPT*CQD;                // 8 MB
    u16* wbf = vbf + (size_t)NB*C_IN*NPT;               // 192 KB
    float* fp    = (float*)(wbf + 384*256);
    float* bias  = fp;                                  // 384
    float* pmax  = bias + 384;                          // 64 KB
    float* psum  = pmax + (size_t)NB*4*NPT;             // 64 KB
    float* Lrow  = psum + (size_t)NB*4*NPT;             // 64 KB

    prep_kernel<<<dim3(386), 256, 0, stream>>>(wq, bq, wk, bk, wv, bv, wbf, bias);
    proj_kernel<<<dim3(NPT/32, NB), 256, 0, stream>>>(x, wbf, bias, qT, kT, vbf);
    stats_kernel<<<dim3(4, NPT/64, NB), 256, 0, stream>>>(qT, kT, pmax, psum);
    merge_kernel<<<dim3(64), 256, 0, stream>>>(pmax, psum, Lrow);
    attn_kernel<<<dim3(NPT/64, 4, NB), 256, 0, stream>>>(qT, kT, vbf, Lrow, gamma, x, out);
}